// Round 2
// baseline (1284.361 us; speedup 1.0000x reference)
//
#include <hip/hip_runtime.h>

// DeepKoopmanNoDec — fp32 in/out (reference is jnp.float32; round-1 NaN was
// caused by casting fp32 inputs as bf16). Encoder uses bf16 MFMA (z_target
// path) and bf16 hi/lo 3-term MFMA (z_k path, feeds the amplifying scan).
// Scan is pure fp32 VALU with A kept fp32 in LDS.
// Shapes: B=2048, M=64, STATE=32, EMBED=96, LATENT=128, HIDDEN=512.

typedef unsigned short u16;
typedef __attribute__((ext_vector_type(8))) short bf16x8;   // MFMA A/B frag (4 VGPRs)
typedef __attribute__((ext_vector_type(4))) float f32x4;    // MFMA C/D frag

// ws layout: hi frags [0,589824) u16, lo frags [589824,1179648) u16, then fp32 z_k
#define OFF_W1 0            // 32 frags   (K=32 , N=512)
#define OFF_W2 16384        // 512 frags  (K=512, N=512)
#define OFF_W3 278528       // 512 frags
#define OFF_WO 540672       // 96 frags   (K=512, N=96)
#define OFF_WL 589824       // lo-part copies, parallel layout
#define OFF_ZK_BYTES 2359296  // = 2*589824*2 bytes; z_k fp32: 2048*128 floats

// d_out regions (float elements): z_pred | x_pred | z_target
#define XPRED_OFF 16777216
#define ZTGT_OFF  20971520

__device__ __forceinline__ float bf2f(u16 u) {
  unsigned int i = ((unsigned int)u) << 16;
  return __builtin_bit_cast(float, i);
}
__device__ __forceinline__ u16 f2bf(float f) {   // round-to-nearest-even
  unsigned int i = __builtin_bit_cast(unsigned int, f);
  i = (i + 0x7FFFu + ((i >> 16) & 1u)) >> 16;
  return (u16)i;
}

// ---------------------------------------------------------------------------
// Prep: swizzle fp32 weights (row-major K x N) into bf16 B-fragment-linear
// layout (hi) + residual (lo). frag f = ct*(K/32)+ks; lane l holds
// W[ks*32+(l>>4)*8+j][ct*16+(l&15)] so the encoder loads one dwordx4/lane.
// ---------------------------------------------------------------------------
__global__ void prep_swizzle(const float* __restrict__ W1, const float* __restrict__ W2,
                             const float* __restrict__ W3, const float* __restrict__ Wo,
                             u16* __restrict__ dst) {
  int f = blockIdx.x;
  int l = threadIdx.x;
  const float* src; int K, N; u16* d;
  if (f < 32)        { src = W1; K = 32;  N = 512; d = dst + OFF_W1; }
  else if (f < 544)  { src = W2; K = 512; N = 512; d = dst + OFF_W2; f -= 32; }
  else if (f < 1056) { src = W3; K = 512; N = 512; d = dst + OFF_W3; f -= 544; }
  else               { src = Wo; K = 512; N = 96;  d = dst + OFF_WO; f -= 1056; }
  const int KF = K >> 5;
  const int ct = f / KF, ks = f - ct * KF;
  const int q = l >> 4, n = l & 15;
  const int kbase = ks * 32 + q * 8;
  const int col = ct * 16 + n;
  bf16x8 vh, vl;
  #pragma unroll
  for (int j = 0; j < 8; ++j) {
    float v = src[(size_t)(kbase + j) * N + col];
    u16 h = f2bf(v);
    vh[j] = (short)h;
    vl[j] = (short)f2bf(v - bf2f(h));
  }
  *(bf16x8*)(d + ((size_t)f * 64 + l) * 8) = vh;
  *(bf16x8*)(d + OFF_WL + ((size_t)f * 64 + l) * 8) = vl;
}

// ---------------------------------------------------------------------------
// Single-precision (plain bf16) MLP layer: C-tile -> LDS -> A-frag transform.
// C layout: col=lane&15, row=(lane>>4)*4+r.  A layout: row=lane&15, k=q*8+j.
// LDS ops within one wave execute in order; asm waitcnt pins the read.
// ---------------------------------------------------------------------------
template<int KF, int NCT, bool RELU>
__device__ __forceinline__ void mlp_layer(const bf16x8* __restrict__ ain,
                                          bf16x8* __restrict__ aout,
                                          const u16* __restrict__ w,
                                          const float* __restrict__ bias,
                                          u16* tile, int q, int n, int l) {
  #pragma unroll
  for (int ctp = 0; ctp < NCT / 2; ++ctp) {
    const int ct0 = 2 * ctp, ct1 = 2 * ctp + 1;
    f32x4 acc0 = {0.f, 0.f, 0.f, 0.f};
    f32x4 acc1 = {0.f, 0.f, 0.f, 0.f};
    #pragma unroll
    for (int ks = 0; ks < KF; ++ks) {
      bf16x8 bf0 = *(const bf16x8*)(w + ((size_t)(ct0 * KF + ks) * 64 + l) * 8);
      bf16x8 bf1 = *(const bf16x8*)(w + ((size_t)(ct1 * KF + ks) * 64 + l) * 8);
      acc0 = __builtin_amdgcn_mfma_f32_16x16x32_bf16(ain[ks], bf0, acc0, 0, 0, 0);
      acc1 = __builtin_amdgcn_mfma_f32_16x16x32_bf16(ain[ks], bf1, acc1, 0, 0, 0);
    }
    const float bia0 = bias[ct0 * 16 + n];
    const float bia1 = bias[ct1 * 16 + n];
    #pragma unroll
    for (int r = 0; r < 4; ++r) {
      float v0 = acc0[r] + bia0;
      float v1 = acc1[r] + bia1;
      if (RELU) { v0 = fmaxf(v0, 0.f); v1 = fmaxf(v1, 0.f); }
      tile[(q * 4 + r) * 40 + n]      = f2bf(v0);
      tile[(q * 4 + r) * 40 + 16 + n] = f2bf(v1);
    }
    __asm__ volatile("s_waitcnt lgkmcnt(0)" ::: "memory");
    aout[ctp] = *(const bf16x8*)(tile + n * 40 + q * 8);
  }
}

// Hi/lo (3-term) MLP layer for the z_k path: ~2^-16 relative error.
template<int KF, int NCT, bool RELU>
__device__ __forceinline__ void mlp_layer2(const bf16x8* __restrict__ inh,
                                           const bf16x8* __restrict__ inl,
                                           bf16x8* __restrict__ outh,
                                           bf16x8* __restrict__ outl,
                                           const u16* __restrict__ wh,
                                           const u16* __restrict__ wl,
                                           const float* __restrict__ bias,
                                           u16* th, u16* tl_, int q, int n, int l) {
  #pragma unroll
  for (int ctp = 0; ctp < NCT / 2; ++ctp) {
    const int ct0 = 2 * ctp, ct1 = 2 * ctp + 1;
    f32x4 acc0 = {0.f, 0.f, 0.f, 0.f};
    f32x4 acc1 = {0.f, 0.f, 0.f, 0.f};
    #pragma unroll
    for (int ks = 0; ks < KF; ++ks) {
      bf16x8 bh0 = *(const bf16x8*)(wh + ((size_t)(ct0 * KF + ks) * 64 + l) * 8);
      bf16x8 bl0 = *(const bf16x8*)(wl + ((size_t)(ct0 * KF + ks) * 64 + l) * 8);
      bf16x8 bh1 = *(const bf16x8*)(wh + ((size_t)(ct1 * KF + ks) * 64 + l) * 8);
      bf16x8 bl1 = *(const bf16x8*)(wl + ((size_t)(ct1 * KF + ks) * 64 + l) * 8);
      acc0 = __builtin_amdgcn_mfma_f32_16x16x32_bf16(inh[ks], bh0, acc0, 0, 0, 0);
      acc0 = __builtin_amdgcn_mfma_f32_16x16x32_bf16(inl[ks], bh0, acc0, 0, 0, 0);
      acc0 = __builtin_amdgcn_mfma_f32_16x16x32_bf16(inh[ks], bl0, acc0, 0, 0, 0);
      acc1 = __builtin_amdgcn_mfma_f32_16x16x32_bf16(inh[ks], bh1, acc1, 0, 0, 0);
      acc1 = __builtin_amdgcn_mfma_f32_16x16x32_bf16(inl[ks], bh1, acc1, 0, 0, 0);
      acc1 = __builtin_amdgcn_mfma_f32_16x16x32_bf16(inh[ks], bl1, acc1, 0, 0, 0);
    }
    const float bia0 = bias[ct0 * 16 + n];
    const float bia1 = bias[ct1 * 16 + n];
    #pragma unroll
    for (int r = 0; r < 4; ++r) {
      float v0 = acc0[r] + bia0;
      float v1 = acc1[r] + bia1;
      if (RELU) { v0 = fmaxf(v0, 0.f); v1 = fmaxf(v1, 0.f); }
      u16 h0 = f2bf(v0), h1v = f2bf(v1);
      th[(q * 4 + r) * 40 + n]       = h0;
      th[(q * 4 + r) * 40 + 16 + n]  = h1v;
      tl_[(q * 4 + r) * 40 + n]      = f2bf(v0 - bf2f(h0));
      tl_[(q * 4 + r) * 40 + 16 + n] = f2bf(v1 - bf2f(h1v));
    }
    __asm__ volatile("s_waitcnt lgkmcnt(0)" ::: "memory");
    outh[ctp] = *(const bf16x8*)(th  + n * 40 + q * 8);
    outl[ctp] = *(const bf16x8*)(tl_ + n * 40 + q * 8);
  }
}

// ---------------------------------------------------------------------------
// z_target encoder: 1 wave = 16 rows of x_next; writes fp32 z_target.
// ---------------------------------------------------------------------------
__global__ __launch_bounds__(256, 2) void encoder_tgt(
    const float* __restrict__ xnext, const u16* __restrict__ wf,
    const float* __restrict__ b1, const float* __restrict__ b2,
    const float* __restrict__ b3, const float* __restrict__ bo_,
    float* __restrict__ ztgt) {
  __shared__ __align__(16) u16 tiles[4][16 * 40];
  const int tid = threadIdx.x;
  const int wv = tid >> 6, l = tid & 63;
  const int q = l >> 4, n = l & 15;
  u16* tile = tiles[wv];
  const size_t row0 = (size_t)blockIdx.x * 64 + (size_t)wv * 16;  // 0..131071
  const float* xsrc = xnext + row0 * 32;
  f32x4 x0 = *(const f32x4*)(xsrc + (size_t)n * 32 + q * 8);
  f32x4 x1 = *(const f32x4*)(xsrc + (size_t)n * 32 + q * 8 + 4);
  bf16x8 ax;
  #pragma unroll
  for (int j = 0; j < 4; ++j) { ax[j] = (short)f2bf(x0[j]); ax[4 + j] = (short)f2bf(x1[j]); }

  bf16x8 h1[16], h2[16];
  mlp_layer<1, 32, true>(&ax, h1, wf + OFF_W1, b1, tile, q, n, l);
  mlp_layer<16, 32, true>(h1, h2, wf + OFF_W2, b2, tile, q, n, l);
  mlp_layer<16, 32, true>(h2, h1, wf + OFF_W3, b3, tile, q, n, l);

  // x part (exact fp32 pass-through)
  *(f32x4*)(ztgt + (row0 + n) * 128 + q * 8)     = x0;
  *(f32x4*)(ztgt + (row0 + n) * 128 + q * 8 + 4) = x1;
  // embed part
  const u16* wo = wf + OFF_WO;
  #pragma unroll
  for (int ct = 0; ct < 6; ++ct) {
    f32x4 acc = {0.f, 0.f, 0.f, 0.f};
    #pragma unroll
    for (int ks = 0; ks < 16; ++ks) {
      bf16x8 bfr = *(const bf16x8*)(wo + ((size_t)(ct * 16 + ks) * 64 + l) * 8);
      acc = __builtin_amdgcn_mfma_f32_16x16x32_bf16(h1[ks], bfr, acc, 0, 0, 0);
    }
    const float bia = bo_[ct * 16 + n];
    #pragma unroll
    for (int r = 0; r < 4; ++r)
      ztgt[(row0 + q * 4 + r) * 128 + 32 + ct * 16 + n] = acc[r] + bia;
  }
}

// ---------------------------------------------------------------------------
// z_k encoder (hi/lo, 32 blocks): writes fp32 z_k to ws for the scan.
// ---------------------------------------------------------------------------
__global__ __launch_bounds__(256, 1) void encoder_zk(
    const float* __restrict__ xk, const u16* __restrict__ wf,
    const float* __restrict__ b1, const float* __restrict__ b2,
    const float* __restrict__ b3, const float* __restrict__ bo_,
    float* __restrict__ zk_out) {
  __shared__ __align__(16) u16 tiles[4][2][16 * 40];
  const int tid = threadIdx.x;
  const int wv = tid >> 6, l = tid & 63;
  const int q = l >> 4, n = l & 15;
  u16* th  = tiles[wv][0];
  u16* tl_ = tiles[wv][1];
  const size_t row0 = (size_t)blockIdx.x * 64 + (size_t)wv * 16;  // 0..2047
  const float* xsrc = xk + row0 * 32;
  f32x4 x0 = *(const f32x4*)(xsrc + (size_t)n * 32 + q * 8);
  f32x4 x1 = *(const f32x4*)(xsrc + (size_t)n * 32 + q * 8 + 4);
  bf16x8 axh, axl;
  #pragma unroll
  for (int j = 0; j < 4; ++j) {
    u16 h0 = f2bf(x0[j]), h1v = f2bf(x1[j]);
    axh[j] = (short)h0;       axh[4 + j] = (short)h1v;
    axl[j] = (short)f2bf(x0[j] - bf2f(h0));
    axl[4 + j] = (short)f2bf(x1[j] - bf2f(h1v));
  }

  bf16x8 ah[16], al[16], bh_[16], bl2[16];
  mlp_layer2<1, 32, true>(&axh, &axl, ah, al, wf + OFF_W1, wf + OFF_WL + OFF_W1, b1, th, tl_, q, n, l);
  mlp_layer2<16, 32, true>(ah, al, bh_, bl2, wf + OFF_W2, wf + OFF_WL + OFF_W2, b2, th, tl_, q, n, l);
  mlp_layer2<16, 32, true>(bh_, bl2, ah, al, wf + OFF_W3, wf + OFF_WL + OFF_W3, b3, th, tl_, q, n, l);

  // x part (exact fp32)
  *(f32x4*)(zk_out + (row0 + n) * 128 + q * 8)     = x0;
  *(f32x4*)(zk_out + (row0 + n) * 128 + q * 8 + 4) = x1;
  const u16* woh = wf + OFF_WO;
  const u16* wol = wf + OFF_WL + OFF_WO;
  #pragma unroll
  for (int ct = 0; ct < 6; ++ct) {
    f32x4 acc = {0.f, 0.f, 0.f, 0.f};
    #pragma unroll
    for (int ks = 0; ks < 16; ++ks) {
      bf16x8 wh8 = *(const bf16x8*)(woh + ((size_t)(ct * 16 + ks) * 64 + l) * 8);
      bf16x8 wl8 = *(const bf16x8*)(wol + ((size_t)(ct * 16 + ks) * 64 + l) * 8);
      acc = __builtin_amdgcn_mfma_f32_16x16x32_bf16(ah[ks], wh8, acc, 0, 0, 0);
      acc = __builtin_amdgcn_mfma_f32_16x16x32_bf16(al[ks], wh8, acc, 0, 0, 0);
      acc = __builtin_amdgcn_mfma_f32_16x16x32_bf16(ah[ks], wl8, acc, 0, 0, 0);
    }
    const float bia = bo_[ct * 16 + n];
    #pragma unroll
    for (int r = 0; r < 4; ++r)
      zk_out[(row0 + q * 4 + r) * 128 + 32 + ct * 16 + n] = acc[r] + bia;
  }
}

// ---------------------------------------------------------------------------
// Scan: z_{s+1} = z_s @ A + u[:,s,:] @ Bmat, 64 steps, all fp32.
// 512 blocks x 4 batch rows. A^T in LDS (fp32, stride 132: f32x4 reads are
// 2-way-conflict = free), z ping-pong in LDS, one barrier per step.
// ---------------------------------------------------------------------------
#define AT_S 132
__global__ __launch_bounds__(256) void scan_kernel(
    const float* __restrict__ zk, const float* __restrict__ Af,
    const float* __restrict__ Bm, const float* __restrict__ useq,
    float* __restrict__ zpred, float* __restrict__ xpred) {
  __shared__ __align__(16) float At[128 * AT_S];   // At[c][k] = A[k][c]
  __shared__ __align__(16) float Bmf[8 * 128];
  __shared__ __align__(16) float zbuf[2][512];
  const int t = threadIdx.x;
  const int b0 = blockIdx.x * 4;
  for (int i = t; i < 16384; i += 256) {           // transpose A (coalesced reads)
    At[(i & 127) * AT_S + (i >> 7)] = Af[i];
  }
  for (int i = t; i < 1024; i += 256) Bmf[i] = Bm[i];
  for (int i = t; i < 512; i += 256) zbuf[0][i] = zk[(size_t)b0 * 128 + i];
  __syncthreads();

  const int wv = t >> 6;
  const int c  = (t & 63) + (wv & 1) * 64;
  const int rh = wv >> 1;
  const int r0 = rh * 2, r1 = rh * 2 + 1;
  float bm[8];
  #pragma unroll
  for (int j = 0; j < 8; ++j) bm[j] = Bmf[j * 128 + c];
  const float* arow = At + (size_t)c * AT_S;
  const size_t o0 = (size_t)(b0 + r0) * 64;        // (b) * M
  const size_t o1 = (size_t)(b0 + r1) * 64;

  int cur = 0;
  for (int s = 0; s < 64; ++s) {
    f32x4 ua0 = *(const f32x4*)(useq + (o0 + s) * 8);
    f32x4 ub0 = *(const f32x4*)(useq + (o0 + s) * 8 + 4);
    f32x4 ua1 = *(const f32x4*)(useq + (o1 + s) * 8);
    f32x4 ub1 = *(const f32x4*)(useq + (o1 + s) * 8 + 4);
    float acc0 = 0.f, acc1 = 0.f;
    #pragma unroll
    for (int j = 0; j < 4; ++j) {
      acc0 += ua0[j] * bm[j] + ub0[j] * bm[4 + j];
      acc1 += ua1[j] * bm[j] + ub1[j] * bm[4 + j];
    }
    const float* z0 = &zbuf[cur][r0 * 128];
    const float* z1 = &zbuf[cur][r1 * 128];
    #pragma unroll
    for (int k = 0; k < 128; k += 4) {
      f32x4 a  = *(const f32x4*)(arow + k);
      f32x4 za = *(const f32x4*)(z0 + k);
      f32x4 zc = *(const f32x4*)(z1 + k);
      acc0 += za[0] * a[0] + za[1] * a[1] + za[2] * a[2] + za[3] * a[3];
      acc1 += zc[0] * a[0] + zc[1] * a[1] + zc[2] * a[2] + zc[3] * a[3];
    }
    zbuf[cur ^ 1][r0 * 128 + c] = acc0;
    zbuf[cur ^ 1][r1 * 128 + c] = acc1;
    zpred[(o0 + s) * 128 + c] = acc0;
    zpred[(o1 + s) * 128 + c] = acc1;
    if (c < 32) {
      xpred[(o0 + s) * 32 + c] = acc0;
      xpred[(o1 + s) * 32 + c] = acc1;
    }
    __syncthreads();
    cur ^= 1;
  }
}

// ---------------------------------------------------------------------------
extern "C" void kernel_launch(void* const* d_in, const int* in_sizes, int n_in,
                              void* d_out, int out_size, void* d_ws, size_t ws_size,
                              hipStream_t stream) {
  (void)in_sizes; (void)n_in; (void)out_size; (void)ws_size;
  const float* xk    = (const float*)d_in[0];
  const float* useq  = (const float*)d_in[1];
  const float* xnext = (const float*)d_in[2];
  const float* W1 = (const float*)d_in[3];
  const float* b1 = (const float*)d_in[4];
  const float* W2 = (const float*)d_in[5];
  const float* b2 = (const float*)d_in[6];
  const float* W3 = (const float*)d_in[7];
  const float* b3 = (const float*)d_in[8];
  const float* Wo = (const float*)d_in[9];
  const float* bo = (const float*)d_in[10];
  const float* A  = (const float*)d_in[11];
  const float* Bm = (const float*)d_in[12];

  float* out   = (float*)d_out;
  float* zpred = out;
  float* xpred = out + XPRED_OFF;
  float* ztgt  = out + ZTGT_OFF;
  u16*   wf    = (u16*)d_ws;
  float* zkw   = (float*)((char*)d_ws + OFF_ZK_BYTES);

  prep_swizzle<<<1152, 64, 0, stream>>>(W1, W2, W3, Wo, wf);
  encoder_zk<<<32, 256, 0, stream>>>(xk, wf, b1, b2, b3, bo, zkw);
  scan_kernel<<<512, 256, 0, stream>>>(zkw, A, Bm, useq, zpred, xpred);
  encoder_tgt<<<2048, 256, 0, stream>>>(xnext, wf, b1, b2, b3, bo, ztgt);
}

// Round 3
// 659.868 us; speedup vs baseline: 1.9464x; 1.9464x over previous
//
#include <hip/hip_runtime.h>

// DeepKoopmanNoDec — fp32 in/out. R3: (1) z_k path rewritten as exact-fp32
// VALU kernel (256 blocks; old MFMA hi/lo version ran at 1.5% occupancy,
// 530us). (2) encoder_tgt restructured: 4 waves/block share weights staged
// into LDS via global_load_lds (width 16), double-buffered ct-pair tiles —
// cuts L2 weight traffic 4x (9.4 GB -> 2.36 GB); new bound is LDS read BW.
// Shapes: B=2048, M=64, STATE=32, EMBED=96, LATENT=128, HIDDEN=512.

typedef unsigned short u16;
typedef __attribute__((ext_vector_type(8))) short bf16x8;   // MFMA A/B frag (4 VGPRs)
typedef __attribute__((ext_vector_type(4))) float f32x4;    // MFMA C/D frag

// ws layout: bf16 B-frag weights (hi only), then fp32 z_k
#define OFF_W1 0              // 32 frags   (K=32 , N=512)
#define OFF_W2 16384          // 512 frags  (K=512, N=512)
#define OFF_W3 278528         // 512 frags
#define OFF_WO 540672         // 96 frags   (K=512, N=96)
#define OFF_ZK_BYTES 1179648  // fp32 z_k: 2048*128 floats

// d_out regions (float elements): z_pred | x_pred | z_target
#define XPRED_OFF 16777216
#define ZTGT_OFF  20971520

__device__ __forceinline__ float bf2f(u16 u) {
  unsigned int i = ((unsigned int)u) << 16;
  return __builtin_bit_cast(float, i);
}
__device__ __forceinline__ u16 f2bf(float f) {   // round-to-nearest-even
  unsigned int i = __builtin_bit_cast(unsigned int, f);
  i = (i + 0x7FFFu + ((i >> 16) & 1u)) >> 16;
  return (u16)i;
}

// ---------------------------------------------------------------------------
// Prep: swizzle fp32 weights (row-major K x N) into bf16 B-fragment-linear
// layout. frag f = ct*(K/32)+ks; lane l holds W[ks*32+(l>>4)*8+j][ct*16+(l&15)]
// at u16 offset f*512 + l*8 -> one dwordx4 per lane, and global_load_lds
// width-16 stages one frag per instruction (lane l lands at lds+16*l).
// ---------------------------------------------------------------------------
__global__ void prep_swizzle(const float* __restrict__ W1, const float* __restrict__ W2,
                             const float* __restrict__ W3, const float* __restrict__ Wo,
                             u16* __restrict__ dst) {
  int f = blockIdx.x;
  int l = threadIdx.x;
  const float* src; int K, N; u16* d;
  if (f < 32)        { src = W1; K = 32;  N = 512; d = dst + OFF_W1; }
  else if (f < 544)  { src = W2; K = 512; N = 512; d = dst + OFF_W2; f -= 32; }
  else if (f < 1056) { src = W3; K = 512; N = 512; d = dst + OFF_W3; f -= 544; }
  else               { src = Wo; K = 512; N = 96;  d = dst + OFF_WO; f -= 1056; }
  const int KF = K >> 5;
  const int ct = f / KF, ks = f - ct * KF;
  const int q = l >> 4, n = l & 15;
  const int kbase = ks * 32 + q * 8;
  const int col = ct * 16 + n;
  bf16x8 vh;
  #pragma unroll
  for (int j = 0; j < 8; ++j)
    vh[j] = (short)f2bf(src[(size_t)(kbase + j) * N + col]);
  *(bf16x8*)(d + ((size_t)f * 64 + l) * 8) = vh;
}

// ---------------------------------------------------------------------------
// Async stage of 32 frags (32 KB) into LDS: wave wv stages frags [wv*8,wv*8+8).
// Per instr: lane l reads src+frag*512+l*8 (16B), HW writes lds+frag*512+16*l.
// ---------------------------------------------------------------------------
__device__ __forceinline__ void stage32(u16* sb, const u16* src, int wv, int l) {
  const int f0 = wv * 8;
  #pragma unroll
  for (int i = 0; i < 8; ++i) {
    __builtin_amdgcn_global_load_lds(
        (const __attribute__((address_space(1))) unsigned int*)(src + (size_t)(f0 + i) * 512 + l * 8),
        (__attribute__((address_space(3))) unsigned int*)(sb + (size_t)(f0 + i) * 512),
        16, 0, 0);
  }
}

// Consume a staged ct-pair (32 frags, KF=16): 32 MFMA + bias/relu + C->A
// transform via per-wave LDS tile. C layout: col=lane&15,row=(lane>>4)*4+r;
// A layout: row=lane&15, k=(lane>>4)*8+j. Wave-private tile; DS in-order.
__device__ __forceinline__ bf16x8 consume_pair16(const u16* sb, const bf16x8* ain,
                                                 const float* __restrict__ bias, int ct0,
                                                 u16* tile, int q, int n, int l) {
  f32x4 acc0 = {0.f, 0.f, 0.f, 0.f};
  f32x4 acc1 = {0.f, 0.f, 0.f, 0.f};
  #pragma unroll
  for (int ks = 0; ks < 16; ++ks) {
    bf16x8 w0 = *(const bf16x8*)(sb + (size_t)ks * 512 + l * 8);
    bf16x8 w1 = *(const bf16x8*)(sb + (size_t)(16 + ks) * 512 + l * 8);
    acc0 = __builtin_amdgcn_mfma_f32_16x16x32_bf16(ain[ks], w0, acc0, 0, 0, 0);
    acc1 = __builtin_amdgcn_mfma_f32_16x16x32_bf16(ain[ks], w1, acc1, 0, 0, 0);
  }
  const float bia0 = bias[ct0 * 16 + n];
  const float bia1 = bias[ct0 * 16 + 16 + n];
  #pragma unroll
  for (int r = 0; r < 4; ++r) {
    float v0 = fmaxf(acc0[r] + bia0, 0.f);
    float v1 = fmaxf(acc1[r] + bia1, 0.f);
    tile[(q * 4 + r) * 40 + n]      = f2bf(v0);
    tile[(q * 4 + r) * 40 + 16 + n] = f2bf(v1);
  }
  __asm__ volatile("s_waitcnt lgkmcnt(0)" ::: "memory");
  return *(const bf16x8*)(tile + n * 40 + q * 8);
}

// ---------------------------------------------------------------------------
// z_target encoder: block = 64 rows (4 waves x 16). Weights staged to LDS in
// 32KB ct-pair tiles, double-buffered; stage for iter p+1 issued AFTER the
// barrier so the barrier's vmcnt(0) drain covers loads that had a full
// consume (~1.5k cyc) to complete.
// ---------------------------------------------------------------------------
__global__ __launch_bounds__(256, 2) void encoder_tgt(
    const float* __restrict__ xnext, const u16* __restrict__ wf,
    const float* __restrict__ b1, const float* __restrict__ b2,
    const float* __restrict__ b3, const float* __restrict__ bo_,
    float* __restrict__ ztgt) {
  __shared__ __align__(16) u16 sbuf[2][32 * 512];   // 2 x 32KB staging
  __shared__ __align__(16) u16 tiles[4][16 * 40];   // per-wave transform tiles
  const int tid = threadIdx.x;
  const int wv = tid >> 6, l = tid & 63;
  const int q = l >> 4, n = l & 15;
  u16* tile = tiles[wv];
  const size_t row0 = (size_t)blockIdx.x * 64 + (size_t)wv * 16;
  const float* xsrc = xnext + row0 * 32;
  f32x4 x0 = *(const f32x4*)(xsrc + (size_t)n * 32 + q * 8);
  f32x4 x1 = *(const f32x4*)(xsrc + (size_t)n * 32 + q * 8 + 4);
  bf16x8 ax;
  #pragma unroll
  for (int j = 0; j < 4; ++j) { ax[j] = (short)f2bf(x0[j]); ax[4 + j] = (short)f2bf(x1[j]); }
  // x pass-through (exact fp32)
  *(f32x4*)(ztgt + (row0 + n) * 128 + q * 8)     = x0;
  *(f32x4*)(ztgt + (row0 + n) * 128 + q * 8 + 4) = x1;

  stage32(sbuf[0], wf + OFF_W1, wv, l);             // W1: all 32 frags = 32KB
  __syncthreads();

  bf16x8 hA[16], hB[16];
  // ---- layer 1 (KF=1) from sbuf[0]; stage W2 pair0 into sbuf[1] ----
  stage32(sbuf[1], wf + OFF_W2, wv, l);
  #pragma unroll
  for (int ctp = 0; ctp < 16; ++ctp) {
    bf16x8 w0 = *(const bf16x8*)(sbuf[0] + (size_t)(2 * ctp) * 512 + l * 8);
    bf16x8 w1 = *(const bf16x8*)(sbuf[0] + (size_t)(2 * ctp + 1) * 512 + l * 8);
    f32x4 acc0 = {0.f, 0.f, 0.f, 0.f};
    f32x4 acc1 = {0.f, 0.f, 0.f, 0.f};
    acc0 = __builtin_amdgcn_mfma_f32_16x16x32_bf16(ax, w0, acc0, 0, 0, 0);
    acc1 = __builtin_amdgcn_mfma_f32_16x16x32_bf16(ax, w1, acc1, 0, 0, 0);
    const float bia0 = b1[2 * ctp * 16 + n];
    const float bia1 = b1[(2 * ctp + 1) * 16 + n];
    #pragma unroll
    for (int r = 0; r < 4; ++r) {
      tile[(q * 4 + r) * 40 + n]      = f2bf(fmaxf(acc0[r] + bia0, 0.f));
      tile[(q * 4 + r) * 40 + 16 + n] = f2bf(fmaxf(acc1[r] + bia1, 0.f));
    }
    __asm__ volatile("s_waitcnt lgkmcnt(0)" ::: "memory");
    hA[ctp] = *(const bf16x8*)(tile + n * 40 + q * 8);
  }
  __syncthreads();

  int cur = 1;
  // ---- layer 2: 16 pairs, hA -> hB ----
  #pragma unroll
  for (int p = 0; p < 16; ++p) {
    stage32(sbuf[cur ^ 1], (p < 15) ? (wf + OFF_W2 + (size_t)(p + 1) * 16384)
                                    : (wf + OFF_W3), wv, l);
    hB[p] = consume_pair16(sbuf[cur], hA, b2, 2 * p, tile, q, n, l);
    __syncthreads();
    cur ^= 1;
  }
  // ---- layer 3: 16 pairs, hB -> hA ----
  #pragma unroll
  for (int p = 0; p < 16; ++p) {
    stage32(sbuf[cur ^ 1], (p < 15) ? (wf + OFF_W3 + (size_t)(p + 1) * 16384)
                                    : (wf + OFF_WO), wv, l);
    hA[p] = consume_pair16(sbuf[cur], hB, b3, 2 * p, tile, q, n, l);
    __syncthreads();
    cur ^= 1;
  }
  // ---- output layer: 3 pairs (6 cts), hA -> ztgt ----
  #pragma unroll
  for (int p = 0; p < 3; ++p) {
    if (p < 2) stage32(sbuf[cur ^ 1], wf + OFF_WO + (size_t)(p + 1) * 16384, wv, l);
    f32x4 acc0 = {0.f, 0.f, 0.f, 0.f};
    f32x4 acc1 = {0.f, 0.f, 0.f, 0.f};
    #pragma unroll
    for (int ks = 0; ks < 16; ++ks) {
      bf16x8 w0 = *(const bf16x8*)(sbuf[cur] + (size_t)ks * 512 + l * 8);
      bf16x8 w1 = *(const bf16x8*)(sbuf[cur] + (size_t)(16 + ks) * 512 + l * 8);
      acc0 = __builtin_amdgcn_mfma_f32_16x16x32_bf16(hA[ks], w0, acc0, 0, 0, 0);
      acc1 = __builtin_amdgcn_mfma_f32_16x16x32_bf16(hA[ks], w1, acc1, 0, 0, 0);
    }
    const float bia0 = bo_[2 * p * 16 + n];
    const float bia1 = bo_[(2 * p + 1) * 16 + n];
    #pragma unroll
    for (int r = 0; r < 4; ++r) {
      ztgt[(row0 + q * 4 + r) * 128 + 32 + 2 * p * 16 + n]      = acc0[r] + bia0;
      ztgt[(row0 + q * 4 + r) * 128 + 32 + (2 * p + 1) * 16 + n] = acc1[r] + bia1;
    }
    __syncthreads();
    cur ^= 1;
  }
}

// ---------------------------------------------------------------------------
// z_k encoder — exact fp32 VALU (only 2048 rows: 2.4 GFLOP, parallelism
// matters more than MFMA). Block = 8 rows, 256 threads, thread owns cols
// {t, t+256}; h ping-pong in LDS (writes coalesced, reads broadcast).
// ---------------------------------------------------------------------------
__global__ __launch_bounds__(256) void encoder_zk_f32(
    const float* __restrict__ xk,
    const float* __restrict__ W1, const float* __restrict__ b1,
    const float* __restrict__ W2, const float* __restrict__ b2,
    const float* __restrict__ W3, const float* __restrict__ b3,
    const float* __restrict__ Wo, const float* __restrict__ bo_,
    float* __restrict__ zk_out) {
  __shared__ __align__(16) float hb[2][8][512];
  __shared__ __align__(16) float xb[8][32];
  const int t = threadIdx.x;
  const int row0 = blockIdx.x * 8;
  {
    int r = t >> 5, j = t & 31;
    float v = xk[(size_t)(row0 + r) * 32 + j];
    xb[r][j] = v;
    zk_out[(size_t)(row0 + r) * 128 + j] = v;      // x pass-through
  }
  __syncthreads();
  const int c0 = t, c1 = t + 256;
  // layer 1: K=32, xb -> hb[0]
  {
    float a0[8], a1[8];
    const float i0 = b1[c0], i1 = b1[c1];
    #pragma unroll
    for (int r = 0; r < 8; ++r) { a0[r] = i0; a1[r] = i1; }
    for (int k = 0; k < 32; k += 4) {
      float w00 = W1[(size_t)(k+0)*512 + c0], w10 = W1[(size_t)(k+0)*512 + c1];
      float w01 = W1[(size_t)(k+1)*512 + c0], w11 = W1[(size_t)(k+1)*512 + c1];
      float w02 = W1[(size_t)(k+2)*512 + c0], w12 = W1[(size_t)(k+2)*512 + c1];
      float w03 = W1[(size_t)(k+3)*512 + c0], w13 = W1[(size_t)(k+3)*512 + c1];
      #pragma unroll
      for (int r = 0; r < 8; ++r) {
        f32x4 z = *(const f32x4*)&xb[r][k];
        a0[r] += z[0]*w00 + z[1]*w01 + z[2]*w02 + z[3]*w03;
        a1[r] += z[0]*w10 + z[1]*w11 + z[2]*w12 + z[3]*w13;
      }
    }
    #pragma unroll
    for (int r = 0; r < 8; ++r) { hb[0][r][c0] = fmaxf(a0[r], 0.f); hb[0][r][c1] = fmaxf(a1[r], 0.f); }
  }
  __syncthreads();
  // layers 2,3: K=512
  #pragma unroll
  for (int lyr = 0; lyr < 2; ++lyr) {
    const float* W = lyr ? W3 : W2;
    const float* bb = lyr ? b3 : b2;
    const float (*hin)[512] = hb[lyr & 1];
    float (*hout)[512] = hb[(lyr & 1) ^ 1];
    float a0[8], a1[8];
    const float i0 = bb[c0], i1 = bb[c1];
    #pragma unroll
    for (int r = 0; r < 8; ++r) { a0[r] = i0; a1[r] = i1; }
    for (int k = 0; k < 512; k += 4) {
      float w00 = W[(size_t)(k+0)*512 + c0], w10 = W[(size_t)(k+0)*512 + c1];
      float w01 = W[(size_t)(k+1)*512 + c0], w11 = W[(size_t)(k+1)*512 + c1];
      float w02 = W[(size_t)(k+2)*512 + c0], w12 = W[(size_t)(k+2)*512 + c1];
      float w03 = W[(size_t)(k+3)*512 + c0], w13 = W[(size_t)(k+3)*512 + c1];
      #pragma unroll
      for (int r = 0; r < 8; ++r) {
        f32x4 z = *(const f32x4*)&hin[r][k];
        a0[r] += z[0]*w00 + z[1]*w01 + z[2]*w02 + z[3]*w03;
        a1[r] += z[0]*w10 + z[1]*w11 + z[2]*w12 + z[3]*w13;
      }
    }
    #pragma unroll
    for (int r = 0; r < 8; ++r) { hout[r][c0] = fmaxf(a0[r], 0.f); hout[r][c1] = fmaxf(a1[r], 0.f); }
    __syncthreads();
  }
  // output layer: N=96, threads t<96 each own one col
  if (t < 96) {
    float a[8];
    const float i0 = bo_[t];
    #pragma unroll
    for (int r = 0; r < 8; ++r) a[r] = i0;
    for (int k = 0; k < 512; k += 4) {
      float w0 = Wo[(size_t)(k+0)*96 + t];
      float w1 = Wo[(size_t)(k+1)*96 + t];
      float w2 = Wo[(size_t)(k+2)*96 + t];
      float w3 = Wo[(size_t)(k+3)*96 + t];
      #pragma unroll
      for (int r = 0; r < 8; ++r) {
        f32x4 z = *(const f32x4*)&hb[0][r][k];
        a[r] += z[0]*w0 + z[1]*w1 + z[2]*w2 + z[3]*w3;
      }
    }
    #pragma unroll
    for (int r = 0; r < 8; ++r)
      zk_out[(size_t)(row0 + r) * 128 + 32 + t] = a[r];
  }
}

// ---------------------------------------------------------------------------
// Scan: z_{s+1} = z_s @ A + u[:,s,:] @ Bmat, 64 steps, all fp32 (unchanged).
// ---------------------------------------------------------------------------
#define AT_S 132
__global__ __launch_bounds__(256) void scan_kernel(
    const float* __restrict__ zk, const float* __restrict__ Af,
    const float* __restrict__ Bm, const float* __restrict__ useq,
    float* __restrict__ zpred, float* __restrict__ xpred) {
  __shared__ __align__(16) float At[128 * AT_S];   // At[c][k] = A[k][c]
  __shared__ __align__(16) float Bmf[8 * 128];
  __shared__ __align__(16) float zbuf[2][512];
  const int t = threadIdx.x;
  const int b0 = blockIdx.x * 4;
  for (int i = t; i < 16384; i += 256)
    At[(i & 127) * AT_S + (i >> 7)] = Af[i];
  for (int i = t; i < 1024; i += 256) Bmf[i] = Bm[i];
  for (int i = t; i < 512; i += 256) zbuf[0][i] = zk[(size_t)b0 * 128 + i];
  __syncthreads();

  const int wv = t >> 6;
  const int c  = (t & 63) + (wv & 1) * 64;
  const int rh = wv >> 1;
  const int r0 = rh * 2, r1 = rh * 2 + 1;
  float bm[8];
  #pragma unroll
  for (int j = 0; j < 8; ++j) bm[j] = Bmf[j * 128 + c];
  const float* arow = At + (size_t)c * AT_S;
  const size_t o0 = (size_t)(b0 + r0) * 64;
  const size_t o1 = (size_t)(b0 + r1) * 64;

  int cur = 0;
  for (int s = 0; s < 64; ++s) {
    f32x4 ua0 = *(const f32x4*)(useq + (o0 + s) * 8);
    f32x4 ub0 = *(const f32x4*)(useq + (o0 + s) * 8 + 4);
    f32x4 ua1 = *(const f32x4*)(useq + (o1 + s) * 8);
    f32x4 ub1 = *(const f32x4*)(useq + (o1 + s) * 8 + 4);
    float acc0 = 0.f, acc1 = 0.f;
    #pragma unroll
    for (int j = 0; j < 4; ++j) {
      acc0 += ua0[j] * bm[j] + ub0[j] * bm[4 + j];
      acc1 += ua1[j] * bm[j] + ub1[j] * bm[4 + j];
    }
    const float* z0 = &zbuf[cur][r0 * 128];
    const float* z1 = &zbuf[cur][r1 * 128];
    #pragma unroll
    for (int k = 0; k < 128; k += 4) {
      f32x4 a  = *(const f32x4*)(arow + k);
      f32x4 za = *(const f32x4*)(z0 + k);
      f32x4 zc = *(const f32x4*)(z1 + k);
      acc0 += za[0] * a[0] + za[1] * a[1] + za[2] * a[2] + za[3] * a[3];
      acc1 += zc[0] * a[0] + zc[1] * a[1] + zc[2] * a[2] + zc[3] * a[3];
    }
    zbuf[cur ^ 1][r0 * 128 + c] = acc0;
    zbuf[cur ^ 1][r1 * 128 + c] = acc1;
    zpred[(o0 + s) * 128 + c] = acc0;
    zpred[(o1 + s) * 128 + c] = acc1;
    if (c < 32) {
      xpred[(o0 + s) * 32 + c] = acc0;
      xpred[(o1 + s) * 32 + c] = acc1;
    }
    __syncthreads();
    cur ^= 1;
  }
}

// ---------------------------------------------------------------------------
extern "C" void kernel_launch(void* const* d_in, const int* in_sizes, int n_in,
                              void* d_out, int out_size, void* d_ws, size_t ws_size,
                              hipStream_t stream) {
  (void)in_sizes; (void)n_in; (void)out_size; (void)ws_size;
  const float* xk    = (const float*)d_in[0];
  const float* useq  = (const float*)d_in[1];
  const float* xnext = (const float*)d_in[2];
  const float* W1 = (const float*)d_in[3];
  const float* b1 = (const float*)d_in[4];
  const float* W2 = (const float*)d_in[5];
  const float* b2 = (const float*)d_in[6];
  const float* W3 = (const float*)d_in[7];
  const float* b3 = (const float*)d_in[8];
  const float* Wo = (const float*)d_in[9];
  const float* bo = (const float*)d_in[10];
  const float* A  = (const float*)d_in[11];
  const float* Bm = (const float*)d_in[12];

  float* out   = (float*)d_out;
  float* zpred = out;
  float* xpred = out + XPRED_OFF;
  float* ztgt  = out + ZTGT_OFF;
  u16*   wf    = (u16*)d_ws;
  float* zkw   = (float*)((char*)d_ws + OFF_ZK_BYTES);

  prep_swizzle<<<1152, 64, 0, stream>>>(W1, W2, W3, Wo, wf);
  encoder_zk_f32<<<256, 256, 0, stream>>>(xk, W1, b1, W2, b2, W3, b3, Wo, bo, zkw);
  scan_kernel<<<512, 256, 0, stream>>>(zkw, A, Bm, useq, zpred, xpred);
  encoder_tgt<<<2048, 256, 0, stream>>>(xnext, wf, b1, b2, b3, bo, ztgt);
}